// Round 7
// baseline (374.125 us; speedup 1.0000x reference)
//
#include <hip/hip_runtime.h>
#include <hip/hip_bf16.h>
#include <stdint.h>

#define B_SZ 8192
#define D_SZ 512
#define U_SZ 512
#define M_SZ 16
#define K_SZ 64

typedef short bf16x8 __attribute__((ext_vector_type(8)));
typedef float f32x4 __attribute__((ext_vector_type(4)));

__device__ __forceinline__ unsigned short f2bf(float f) {
  union { float f; unsigned u; } v; v.f = f;
  unsigned r = v.u + 0x7fffu + ((v.u >> 16) & 1u);
  return (unsigned short)(r >> 16);
}

// =====================================================================
// prep1: role-split single launch. ALL outputs are fragment-linear bf16.
//  [0,2048):    kernels [M][D][U] f32 -> kbf [m][ut16][kt][j2][h][lane][8]
//  [2048,2056): key_kernel [D][K]     -> wkbf [kt][j4][h][lane][8]
//  [2056,2568): x [B][D]              -> xbf [bt][kt][i8][h][lane][8]
// lane = quad*16+lane16; elem e -> k = kt*64 + h*32 + quad*8 + e.
// =====================================================================
__global__ __launch_bounds__(256) void prep1(
    const float* __restrict__ x, const float* __restrict__ key_kernel,
    const float* __restrict__ kernels, unsigned short* __restrict__ xbf,
    unsigned short* __restrict__ kbf, unsigned short* __restrict__ wkbf) {
  __shared__ float tf[32][65];
  int bid = blockIdx.x;
  int t = threadIdx.x;

  if (bid < 2048) {
    // ---- role T: kernels -> kbf (frag-linear B operand, 32-col tiles) ----
    int m = bid >> 7;
    int rem = bid & 127;
    int a = (rem >> 3) & 15;  // 32-d tile
    int ut64 = rem & 7;       // 64-u tile
    int d0 = a * 32, u0 = ut64 * 64;
    {
      int dr = t >> 4, uc = t & 15;
      const float* src = kernels + ((size_t)m * D_SZ + d0 + dr) * U_SZ + u0 + uc * 4;
      float4 aa = *(const float4*)src;
      float4 bb = *(const float4*)(src + (size_t)16 * U_SZ);
      tf[dr][uc * 4 + 0] = aa.x; tf[dr][uc * 4 + 1] = aa.y;
      tf[dr][uc * 4 + 2] = aa.z; tf[dr][uc * 4 + 3] = aa.w;
      tf[dr + 16][uc * 4 + 0] = bb.x; tf[dr + 16][uc * 4 + 1] = bb.y;
      tf[dr + 16][uc * 4 + 2] = bb.z; tf[dr + 16][uc * 4 + 3] = bb.w;
    }
    __syncthreads();
    {
      int ur = t >> 2, dc = t & 3;  // u-row 0..63, d-oct 0..3
      int kt = a >> 1, h = a & 1;
      int ut16 = ut64 * 2 + (ur >> 5);
      int j2 = (ur >> 4) & 1;
      int lane16 = ur & 15;
      unsigned short* dst = kbf +
          (((((size_t)m * 16 + ut16) * 8 + kt) * 2 + j2) * 2 + h) * 512 +
          ((size_t)dc * 16 + lane16) * 8;
      ushort4 lo, hi;
      lo.x = f2bf(tf[dc * 8 + 0][ur]); lo.y = f2bf(tf[dc * 8 + 1][ur]);
      lo.z = f2bf(tf[dc * 8 + 2][ur]); lo.w = f2bf(tf[dc * 8 + 3][ur]);
      hi.x = f2bf(tf[dc * 8 + 4][ur]); hi.y = f2bf(tf[dc * 8 + 5][ur]);
      hi.z = f2bf(tf[dc * 8 + 6][ur]); hi.w = f2bf(tf[dc * 8 + 7][ur]);
      *(ushort4*)dst = lo;
      *(ushort4*)(dst + 4) = hi;
    }
    return;
  }

  if (bid < 2056) {
    // ---- role W: key_kernel -> wkbf ----
    int kt = bid - 2048;
#pragma unroll
    for (int rep = 0; rep < 2; ++rep) {
      int c = rep * 256 + t;
      int j = c >> 7, h = (c >> 6) & 1, quad = (c >> 4) & 3, ln = c & 15;
      int dd = kt * 64 + h * 32 + quad * 8;
      int u = j * 16 + ln;
      unsigned short v[8];
#pragma unroll
      for (int e = 0; e < 8; ++e)
        v[e] = f2bf(key_kernel[(size_t)(dd + e) * K_SZ + u]);
      unsigned short* dst =
          wkbf + ((size_t)((kt * 4 + j) * 2 + h) * 64 + quad * 16 + ln) * 8;
#pragma unroll
      for (int e = 0; e < 8; ++e) dst[e] = v[e];
    }
    return;
  }

  // ---- role X: x -> xbf (frag-linear A operand) ----
  int xb0 = bid - 2056;
  int bt = xb0 >> 3, i = xb0 & 7;
  int b0 = xb0 * 16;
#pragma unroll
  for (int rep = 0; rep < 4; ++rep) {
    int idx = rep * 256 + t;
    int kt = idx >> 7, h = (idx >> 6) & 1, quad = (idx >> 4) & 3, ln = idx & 15;
    const float* src = x + (size_t)(b0 + ln) * D_SZ + kt * 64 + h * 32 + quad * 8;
    float4 a = *(const float4*)src;
    float4 b = *(const float4*)(src + 4);
    ushort4 lo, hi;
    lo.x = f2bf(a.x); lo.y = f2bf(a.y); lo.z = f2bf(a.z); lo.w = f2bf(a.w);
    hi.x = f2bf(b.x); hi.y = f2bf(b.y); hi.z = f2bf(b.z); hi.w = f2bf(b.w);
    unsigned short* dst =
        xbf + ((((size_t)bt * 8 + kt) * 8 + i) * 2 + h) * 512 +
        ((size_t)quad * 16 + ln) * 8;
    *(ushort4*)dst = lo;
    *(ushort4*)(dst + 4) = hi;
  }
}

// =====================================================================
// poly_gemm (fused): per block (128 rows x 32 cols; 1024 blocks = 64bt x 16ut):
//   phase A: keyv[128][64] = x@Wk + bias via MFMA (wave w: rows w*32..+32) -> LDS
//   phase B: sim[16][128] -> LDS (thread = (row, k-half), shfl-combine)
//   main:    64 iters (8 kt x 8 mi), NO barriers, frags direct global->VGPR;
//            waves: half=w>>1 (mode half), rw=w&1 (row half). Wave tile 64x32.
//   epilogue: half-combine via LDS, plain stores (bias folded at kt==0).
// =====================================================================
__global__ __launch_bounds__(256, 4) void poly_gemm(
    const unsigned short* __restrict__ xbf,   // A frag-linear
    const unsigned short* __restrict__ kbf,   // B frag-linear
    const unsigned short* __restrict__ wkbf,  // key_kernel frag-linear
    const float* __restrict__ key_bias, const float* __restrict__ keys_map,
    const float* __restrict__ biases, float* __restrict__ out) {
  __shared__ float smem[128 * 68];  // 34 KB: kv -> sims(0..2048)+sRed(2048..6144)

  int t = threadIdx.x, w = t >> 6, l = t & 63;
  int bid = blockIdx.x;
  int ut = bid & 15, bt = bid >> 4;
  int b0 = bt * 128, u0 = ut * 32;
  int lane16 = l & 15, quad = l >> 4;

  // ---------- phase A: keyv (wave w -> rows w*32..w*32+31) ----------
  {
    f32x4 acc[2][4];
#pragma unroll
    for (int ii = 0; ii < 2; ++ii)
#pragma unroll
      for (int j = 0; j < 4; ++j) acc[ii][j] = (f32x4){0.f, 0.f, 0.f, 0.f};
    for (int kt = 0; kt < 8; ++kt) {
      bf16x8 af[2][2];
#pragma unroll
      for (int ii = 0; ii < 2; ++ii)
#pragma unroll
        for (int h = 0; h < 2; ++h)
          af[ii][h] = *(const bf16x8*)(
              xbf + ((((size_t)bt * 8 + kt) * 8 + w * 2 + ii) * 2 + h) * 512 +
              (size_t)l * 8);
#pragma unroll
      for (int j = 0; j < 4; ++j) {
        bf16x8 bw0 = *(const bf16x8*)(wkbf + ((size_t)((kt * 4 + j) * 2 + 0)) * 512 + (size_t)l * 8);
        bf16x8 bw1 = *(const bf16x8*)(wkbf + ((size_t)((kt * 4 + j) * 2 + 1)) * 512 + (size_t)l * 8);
#pragma unroll
        for (int ii = 0; ii < 2; ++ii) {
          acc[ii][j] = __builtin_amdgcn_mfma_f32_16x16x32_bf16(af[ii][0], bw0, acc[ii][j], 0, 0, 0);
          acc[ii][j] = __builtin_amdgcn_mfma_f32_16x16x32_bf16(af[ii][1], bw1, acc[ii][j], 0, 0, 0);
        }
      }
    }
#pragma unroll
    for (int j = 0; j < 4; ++j) {
      float bc = key_bias[j * 16 + lane16];
#pragma unroll
      for (int ii = 0; ii < 2; ++ii)
#pragma unroll
        for (int r = 0; r < 4; ++r)
          smem[(w * 32 + ii * 16 + quad * 4 + r) * 68 + j * 16 + lane16] =
              acc[ii][j][r] + bc;
    }
  }
  __syncthreads();

  // ---------- phase B: sim[16][128] ----------
  {
    int row = t >> 1, kh = t & 1;
    float kvr[32];
#pragma unroll
    for (int q = 0; q < 8; ++q) {
      float4 v = *(const float4*)&smem[row * 68 + kh * 32 + q * 4];
      kvr[q * 4 + 0] = v.x; kvr[q * 4 + 1] = v.y;
      kvr[q * 4 + 2] = v.z; kvr[q * 4 + 3] = v.w;
    }
    __syncthreads();  // all kv reads done; smem reusable
    float part[16];
#pragma unroll
    for (int m = 0; m < 16; ++m) {
      float d2 = 0.f;
#pragma unroll
      for (int k = 0; k < 32; ++k) {
        float df = kvr[k] - keys_map[m * 64 + kh * 32 + k];
        d2 += df * df;
      }
      part[m] = d2;
    }
#pragma unroll
    for (int m = 0; m < 16; ++m) {
      float d2 = part[m] + __shfl_xor(part[m], 1);
      float s = 1.0f / (sqrtf(d2) + 1.0f);
      if ((m >> 3) == kh) smem[m * 128 + row] = s;  // sims[16][128] @ smem[0..2048]
    }
  }
  __syncthreads();

  // ---------- main loop: no barriers ----------
  int half = w >> 1, rw = w & 1;
  f32x4 facc[4][2];
#pragma unroll
  for (int i = 0; i < 4; ++i)
#pragma unroll
    for (int j = 0; j < 2; ++j) facc[i][j] = (f32x4){0.f, 0.f, 0.f, 0.f};

#pragma unroll 1
  for (int kt = 0; kt < 8; ++kt) {
    bf16x8 af[4][2];
#pragma unroll
    for (int ii = 0; ii < 4; ++ii)
#pragma unroll
      for (int h = 0; h < 2; ++h)
        af[ii][h] = *(const bf16x8*)(
            xbf + ((((size_t)bt * 8 + kt) * 8 + rw * 4 + ii) * 2 + h) * 512 +
            (size_t)l * 8);

#pragma unroll 2
    for (int mi = 0; mi < 8; ++mi) {
      int mode = half * 8 + mi;
      const unsigned short* bb =
          kbf + ((((size_t)mode * 16 + ut) * 8 + kt) * 2) * 2 * 512;
      bf16x8 bfr[2][2];
#pragma unroll
      for (int j = 0; j < 2; ++j)
#pragma unroll
        for (int h = 0; h < 2; ++h)
          bfr[j][h] = *(const bf16x8*)(bb + ((size_t)(j * 2 + h)) * 512 +
                                       (size_t)l * 8);
      f32x4 sv[4];
#pragma unroll
      for (int i = 0; i < 4; ++i)
        sv[i] = *(const f32x4*)&smem[mode * 128 + rw * 64 + i * 16 + quad * 4];

#pragma unroll
      for (int i = 0; i < 4; ++i)
#pragma unroll
        for (int j = 0; j < 2; ++j) {
          f32x4 p = __builtin_amdgcn_mfma_f32_16x16x32_bf16(
              af[i][0], bfr[j][0], (f32x4){0.f, 0.f, 0.f, 0.f}, 0, 0, 0);
          p = __builtin_amdgcn_mfma_f32_16x16x32_bf16(af[i][1], bfr[j][1], p, 0, 0, 0);
#pragma unroll
          for (int r = 0; r < 4; ++r) facc[i][j][r] += sv[i][r] * p[r];
        }

      if (kt == 0) {  // bias term once per mode
        float bbv[2];
#pragma unroll
        for (int j = 0; j < 2; ++j)
          bbv[j] = biases[(size_t)mode * U_SZ + u0 + j * 16 + lane16];
#pragma unroll
        for (int i = 0; i < 4; ++i)
#pragma unroll
          for (int j = 0; j < 2; ++j)
#pragma unroll
            for (int r = 0; r < 4; ++r) facc[i][j][r] += sv[i][r] * bbv[j];
      }
    }
  }

  // ---------- epilogue: combine mode-halves via LDS ----------
  float* sRed = smem + 2048;  // 16 KB region after sims
  __syncthreads();
  if (half == 1) {
#pragma unroll
    for (int i = 0; i < 4; ++i)
#pragma unroll
      for (int r = 0; r < 4; ++r)
#pragma unroll
        for (int j = 0; j < 2; ++j)
          sRed[rw * 2048 + (i * 16 + quad * 4 + r) * 32 + j * 16 + lane16] =
              facc[i][j][r];
  }
  __syncthreads();
  if (half == 0) {
#pragma unroll
    for (int i = 0; i < 4; ++i)
#pragma unroll
      for (int r = 0; r < 4; ++r) {
        int row = b0 + rw * 64 + i * 16 + quad * 4 + r;
        float* orow = out + (size_t)row * U_SZ + u0;
#pragma unroll
        for (int j = 0; j < 2; ++j)
          orow[j * 16 + lane16] =
              (facc[i][j][r] +
               sRed[rw * 2048 + (i * 16 + quad * 4 + r) * 32 + j * 16 + lane16]) *
              0.0625f;
      }
  }
}

extern "C" void kernel_launch(void* const* d_in, const int* in_sizes, int n_in,
                              void* d_out, int out_size, void* d_ws, size_t ws_size,
                              hipStream_t stream) {
  const float* x = (const float*)d_in[0];
  const float* key_kernel = (const float*)d_in[1];
  const float* key_bias = (const float*)d_in[2];
  const float* keys_map = (const float*)d_in[3];
  const float* kernels = (const float*)d_in[4];
  const float* biases = (const float*)d_in[5];
  float* out = (float*)d_out;

  // ws: xbf 8MB | kbf 8MB | wkbf 64KB
  char* p = (char*)d_ws;
  unsigned short* xbf = (unsigned short*)p;  p += (size_t)B_SZ * D_SZ * 2;
  unsigned short* kbf = (unsigned short*)p;  p += (size_t)M_SZ * U_SZ * D_SZ * 2;
  unsigned short* wkbf = (unsigned short*)p;

  prep1<<<dim3(2568), 256, 0, stream>>>(x, key_kernel, kernels, xbf, kbf, wkbf);
  poly_gemm<<<dim3(1024), 256, 0, stream>>>(xbf, kbf, wkbf, key_bias, keys_map,
                                            biases, out);
}

// Round 8
// 291.767 us; speedup vs baseline: 1.2823x; 1.2823x over previous
//
#include <hip/hip_runtime.h>
#include <hip/hip_bf16.h>
#include <stdint.h>

#define B_SZ 8192
#define D_SZ 512
#define U_SZ 512
#define M_SZ 16
#define K_SZ 64

typedef short bf16x8 __attribute__((ext_vector_type(8)));
typedef float f32x4 __attribute__((ext_vector_type(4)));

__device__ __forceinline__ unsigned short f2bf(float f) {
  union { float f; unsigned u; } v; v.f = f;
  unsigned r = v.u + 0x7fffu + ((v.u >> 16) & 1u);
  return (unsigned short)(r >> 16);
}

// =====================================================================
// prep1: role-split single launch. ALL outputs are fragment-linear bf16.
//  [0,2048):    kernels [M][D][U] f32 -> kbf [m][ut16][kt][j2][h][lane][8]
//  [2048,2056): key_kernel [D][K]     -> wkbf [kt][j4][h][lane][8]
//  [2056,2568): x [B][D]              -> xbf [bt][kt][i8][h][lane][8]
// lane = quad*16+lane16; elem e -> k = kt*64 + h*32 + quad*8 + e.
// =====================================================================
__global__ __launch_bounds__(256) void prep1(
    const float* __restrict__ x, const float* __restrict__ key_kernel,
    const float* __restrict__ kernels, unsigned short* __restrict__ xbf,
    unsigned short* __restrict__ kbf, unsigned short* __restrict__ wkbf) {
  __shared__ float tf[32][65];
  int bid = blockIdx.x;
  int t = threadIdx.x;

  if (bid < 2048) {
    // ---- role T: kernels -> kbf (frag-linear B operand, 32-col tiles) ----
    int m = bid >> 7;
    int rem = bid & 127;
    int a = (rem >> 3) & 15;  // 32-d tile
    int ut64 = rem & 7;       // 64-u tile
    int d0 = a * 32, u0 = ut64 * 64;
    {
      int dr = t >> 4, uc = t & 15;
      const float* src = kernels + ((size_t)m * D_SZ + d0 + dr) * U_SZ + u0 + uc * 4;
      float4 aa = *(const float4*)src;
      float4 bb = *(const float4*)(src + (size_t)16 * U_SZ);
      tf[dr][uc * 4 + 0] = aa.x; tf[dr][uc * 4 + 1] = aa.y;
      tf[dr][uc * 4 + 2] = aa.z; tf[dr][uc * 4 + 3] = aa.w;
      tf[dr + 16][uc * 4 + 0] = bb.x; tf[dr + 16][uc * 4 + 1] = bb.y;
      tf[dr + 16][uc * 4 + 2] = bb.z; tf[dr + 16][uc * 4 + 3] = bb.w;
    }
    __syncthreads();
    {
      int ur = t >> 2, dc = t & 3;  // u-row 0..63, d-oct 0..3
      int kt = a >> 1, h = a & 1;
      int ut16 = ut64 * 2 + (ur >> 5);
      int j2 = (ur >> 4) & 1;
      int lane16 = ur & 15;
      unsigned short* dst = kbf +
          (((((size_t)m * 16 + ut16) * 8 + kt) * 2 + j2) * 2 + h) * 512 +
          ((size_t)dc * 16 + lane16) * 8;
      ushort4 lo, hi;
      lo.x = f2bf(tf[dc * 8 + 0][ur]); lo.y = f2bf(tf[dc * 8 + 1][ur]);
      lo.z = f2bf(tf[dc * 8 + 2][ur]); lo.w = f2bf(tf[dc * 8 + 3][ur]);
      hi.x = f2bf(tf[dc * 8 + 4][ur]); hi.y = f2bf(tf[dc * 8 + 5][ur]);
      hi.z = f2bf(tf[dc * 8 + 6][ur]); hi.w = f2bf(tf[dc * 8 + 7][ur]);
      *(ushort4*)dst = lo;
      *(ushort4*)(dst + 4) = hi;
    }
    return;
  }

  if (bid < 2056) {
    // ---- role W: key_kernel -> wkbf ----
    int kt = bid - 2048;
#pragma unroll
    for (int rep = 0; rep < 2; ++rep) {
      int c = rep * 256 + t;
      int j = c >> 7, h = (c >> 6) & 1, quad = (c >> 4) & 3, ln = c & 15;
      int dd = kt * 64 + h * 32 + quad * 8;
      int u = j * 16 + ln;
      unsigned short v[8];
#pragma unroll
      for (int e = 0; e < 8; ++e)
        v[e] = f2bf(key_kernel[(size_t)(dd + e) * K_SZ + u]);
      unsigned short* dst =
          wkbf + ((size_t)((kt * 4 + j) * 2 + h) * 64 + quad * 16 + ln) * 8;
#pragma unroll
      for (int e = 0; e < 8; ++e) dst[e] = v[e];
    }
    return;
  }

  // ---- role X: x -> xbf (frag-linear A operand) ----
  int xb0 = bid - 2056;
  int bt = xb0 >> 3, i = xb0 & 7;
  int b0 = xb0 * 16;
#pragma unroll
  for (int rep = 0; rep < 4; ++rep) {
    int idx = rep * 256 + t;
    int kt = idx >> 7, h = (idx >> 6) & 1, quad = (idx >> 4) & 3, ln = idx & 15;
    const float* src = x + (size_t)(b0 + ln) * D_SZ + kt * 64 + h * 32 + quad * 8;
    float4 a = *(const float4*)src;
    float4 b = *(const float4*)(src + 4);
    ushort4 lo, hi;
    lo.x = f2bf(a.x); lo.y = f2bf(a.y); lo.z = f2bf(a.z); lo.w = f2bf(a.w);
    hi.x = f2bf(b.x); hi.y = f2bf(b.y); hi.z = f2bf(b.z); hi.w = f2bf(b.w);
    unsigned short* dst =
        xbf + ((((size_t)bt * 8 + kt) * 8 + i) * 2 + h) * 512 +
        ((size_t)quad * 16 + ln) * 8;
    *(ushort4*)dst = lo;
    *(ushort4*)(dst + 4) = hi;
  }
}

// =====================================================================
// poly_gemm (fused): per block (128 rows x 32 cols; 1024 blocks):
//   swizzle: xcd=bid&7 -> ut = xcd*2 + ((bid>>3)&1), bt = bid>>4
//            (each XCD sees only 2 kbf ut-slices -> ~1MB L2-resident)
//   phase A: keyv[128][64] = x@Wk + bias via MFMA -> LDS
//   phase B: sim[16][128] -> LDS
//   main:    64 iters (8 kt x 8 mi), NO barriers, frags direct global->VGPR
//   epilogue: half-combine via LDS, plain stores.
// __launch_bounds__(256,2): (256,4) made the allocator clamp to 64 VGPRs ->
// 428 MB scratch spill (round 7). (256,2) gives ~108 VGPRs; HW can still
// co-schedule 4 blocks/CU when VGPR<=128 and LDS 34KB.
// =====================================================================
__global__ __launch_bounds__(256, 2) void poly_gemm(
    const unsigned short* __restrict__ xbf,   // A frag-linear
    const unsigned short* __restrict__ kbf,   // B frag-linear
    const unsigned short* __restrict__ wkbf,  // key_kernel frag-linear
    const float* __restrict__ key_bias, const float* __restrict__ keys_map,
    const float* __restrict__ biases, float* __restrict__ out) {
  __shared__ float smem[128 * 68];  // 34 KB: kv -> sims(0..2048)+sRed(2048..6144)

  int t = threadIdx.x, w = t >> 6, l = t & 63;
  int bid = blockIdx.x;
  int ut = (bid & 7) * 2 + ((bid >> 3) & 1);
  int bt = bid >> 4;
  int b0 = bt * 128, u0 = ut * 32;
  int lane16 = l & 15, quad = l >> 4;

  // ---------- phase A: keyv (wave w -> rows w*32..w*32+31) ----------
  {
    f32x4 acc[2][4];
#pragma unroll
    for (int ii = 0; ii < 2; ++ii)
#pragma unroll
      for (int j = 0; j < 4; ++j) acc[ii][j] = (f32x4){0.f, 0.f, 0.f, 0.f};
    for (int kt = 0; kt < 8; ++kt) {
      bf16x8 af[2][2];
#pragma unroll
      for (int ii = 0; ii < 2; ++ii)
#pragma unroll
        for (int h = 0; h < 2; ++h)
          af[ii][h] = *(const bf16x8*)(
              xbf + ((((size_t)bt * 8 + kt) * 8 + w * 2 + ii) * 2 + h) * 512 +
              (size_t)l * 8);
#pragma unroll
      for (int j = 0; j < 4; ++j) {
        bf16x8 bw0 = *(const bf16x8*)(wkbf + ((size_t)((kt * 4 + j) * 2 + 0)) * 512 + (size_t)l * 8);
        bf16x8 bw1 = *(const bf16x8*)(wkbf + ((size_t)((kt * 4 + j) * 2 + 1)) * 512 + (size_t)l * 8);
#pragma unroll
        for (int ii = 0; ii < 2; ++ii) {
          acc[ii][j] = __builtin_amdgcn_mfma_f32_16x16x32_bf16(af[ii][0], bw0, acc[ii][j], 0, 0, 0);
          acc[ii][j] = __builtin_amdgcn_mfma_f32_16x16x32_bf16(af[ii][1], bw1, acc[ii][j], 0, 0, 0);
        }
      }
    }
#pragma unroll
    for (int j = 0; j < 4; ++j) {
      float bc = key_bias[j * 16 + lane16];
#pragma unroll
      for (int ii = 0; ii < 2; ++ii)
#pragma unroll
        for (int r = 0; r < 4; ++r)
          smem[(w * 32 + ii * 16 + quad * 4 + r) * 68 + j * 16 + lane16] =
              acc[ii][j][r] + bc;
    }
  }
  __syncthreads();

  // ---------- phase B: sim[16][128] ----------
  {
    int row = t >> 1, kh = t & 1;
    float kvr[32];
#pragma unroll
    for (int q = 0; q < 8; ++q) {
      float4 v = *(const float4*)&smem[row * 68 + kh * 32 + q * 4];
      kvr[q * 4 + 0] = v.x; kvr[q * 4 + 1] = v.y;
      kvr[q * 4 + 2] = v.z; kvr[q * 4 + 3] = v.w;
    }
    __syncthreads();  // all kv reads done; smem reusable
    float part[16];
#pragma unroll
    for (int m = 0; m < 16; ++m) {
      float d2 = 0.f;
#pragma unroll
      for (int k = 0; k < 32; ++k) {
        float df = kvr[k] - keys_map[m * 64 + kh * 32 + k];
        d2 += df * df;
      }
      part[m] = d2;
    }
#pragma unroll
    for (int m = 0; m < 16; ++m) {
      float d2 = part[m] + __shfl_xor(part[m], 1);
      float s = 1.0f / (sqrtf(d2) + 1.0f);
      if ((m >> 3) == kh) smem[m * 128 + row] = s;  // sims[16][128]
    }
  }
  __syncthreads();

  // ---------- main loop: no barriers ----------
  int half = w >> 1, rw = w & 1;
  f32x4 facc[4][2];
#pragma unroll
  for (int i = 0; i < 4; ++i)
#pragma unroll
    for (int j = 0; j < 2; ++j) facc[i][j] = (f32x4){0.f, 0.f, 0.f, 0.f};

#pragma unroll 1
  for (int kt = 0; kt < 8; ++kt) {
    bf16x8 af[4][2];
#pragma unroll
    for (int ii = 0; ii < 4; ++ii)
#pragma unroll
      for (int h = 0; h < 2; ++h)
        af[ii][h] = *(const bf16x8*)(
            xbf + ((((size_t)bt * 8 + kt) * 8 + rw * 4 + ii) * 2 + h) * 512 +
            (size_t)l * 8);

#pragma unroll 1
    for (int mi = 0; mi < 8; ++mi) {
      int mode = half * 8 + mi;
      const unsigned short* bb =
          kbf + ((((size_t)mode * 16 + ut) * 8 + kt) * 2) * 2 * 512;
      f32x4 sv[4];
#pragma unroll
      for (int i = 0; i < 4; ++i)
        sv[i] = *(const f32x4*)&smem[mode * 128 + rw * 64 + i * 16 + quad * 4];

#pragma unroll
      for (int j = 0; j < 2; ++j) {
        bf16x8 b0f = *(const bf16x8*)(bb + ((size_t)(j * 2 + 0)) * 512 + (size_t)l * 8);
        bf16x8 b1f = *(const bf16x8*)(bb + ((size_t)(j * 2 + 1)) * 512 + (size_t)l * 8);
#pragma unroll
        for (int i = 0; i < 4; ++i) {
          f32x4 p = __builtin_amdgcn_mfma_f32_16x16x32_bf16(
              af[i][0], b0f, (f32x4){0.f, 0.f, 0.f, 0.f}, 0, 0, 0);
          p = __builtin_amdgcn_mfma_f32_16x16x32_bf16(af[i][1], b1f, p, 0, 0, 0);
#pragma unroll
          for (int r = 0; r < 4; ++r) facc[i][j][r] += sv[i][r] * p[r];
        }
      }

      if (kt == 0) {  // bias term once per mode
        float bbv[2];
#pragma unroll
        for (int j = 0; j < 2; ++j)
          bbv[j] = biases[(size_t)mode * U_SZ + u0 + j * 16 + lane16];
#pragma unroll
        for (int i = 0; i < 4; ++i)
#pragma unroll
          for (int j = 0; j < 2; ++j)
#pragma unroll
            for (int r = 0; r < 4; ++r) facc[i][j][r] += sv[i][r] * bbv[j];
      }
    }
  }

  // ---------- epilogue: combine mode-halves via LDS ----------
  float* sRed = smem + 2048;
  __syncthreads();
  if (half == 1) {
#pragma unroll
    for (int i = 0; i < 4; ++i)
#pragma unroll
      for (int r = 0; r < 4; ++r)
#pragma unroll
        for (int j = 0; j < 2; ++j)
          sRed[rw * 2048 + (i * 16 + quad * 4 + r) * 32 + j * 16 + lane16] =
              facc[i][j][r];
  }
  __syncthreads();
  if (half == 0) {
#pragma unroll
    for (int i = 0; i < 4; ++i)
#pragma unroll
      for (int r = 0; r < 4; ++r) {
        int row = b0 + rw * 64 + i * 16 + quad * 4 + r;
        float* orow = out + (size_t)row * U_SZ + u0;
#pragma unroll
        for (int j = 0; j < 2; ++j)
          orow[j * 16 + lane16] =
              (facc[i][j][r] +
               sRed[rw * 2048 + (i * 16 + quad * 4 + r) * 32 + j * 16 + lane16]) *
              0.0625f;
      }
  }
}

extern "C" void kernel_launch(void* const* d_in, const int* in_sizes, int n_in,
                              void* d_out, int out_size, void* d_ws, size_t ws_size,
                              hipStream_t stream) {
  const float* x = (const float*)d_in[0];
  const float* key_kernel = (const float*)d_in[1];
  const float* key_bias = (const float*)d_in[2];
  const float* keys_map = (const float*)d_in[3];
  const float* kernels = (const float*)d_in[4];
  const float* biases = (const float*)d_in[5];
  float* out = (float*)d_out;

  // ws: xbf 8MB | kbf 8MB | wkbf 64KB
  char* p = (char*)d_ws;
  unsigned short* xbf = (unsigned short*)p;  p += (size_t)B_SZ * D_SZ * 2;
  unsigned short* kbf = (unsigned short*)p;  p += (size_t)M_SZ * U_SZ * D_SZ * 2;
  unsigned short* wkbf = (unsigned short*)p;

  prep1<<<dim3(2568), 256, 0, stream>>>(x, key_kernel, kernels, xbf, kbf, wkbf);
  poly_gemm<<<dim3(1024), 256, 0, stream>>>(xbf, kbf, wkbf, key_bias, keys_map,
                                            biases, out);
}

// Round 9
// 180.642 us; speedup vs baseline: 2.0711x; 1.6152x over previous
//
#include <hip/hip_runtime.h>
#include <hip/hip_bf16.h>
#include <stdint.h>

#define B_SZ 8192
#define D_SZ 512
#define U_SZ 512
#define M_SZ 16
#define K_SZ 64

typedef short bf16x8 __attribute__((ext_vector_type(8)));
typedef float f32x4 __attribute__((ext_vector_type(4)));

__device__ __forceinline__ unsigned short f2bf(float f) {
  union { float f; unsigned u; } v; v.f = f;
  unsigned r = v.u + 0x7fffu + ((v.u >> 16) & 1u);
  return (unsigned short)(r >> 16);
}

// =====================================================================
// prep1: role-split single launch. ALL outputs are fragment-linear bf16.
//  [0,2048):    kernels [M][D][U] f32 -> kbf [m][ut16][kt][j2][h][lane][8]
//  [2048,2056): key_kernel [D][K]     -> wkbf [kt][j4][h][lane][8]
//  [2056,2568): x [B][D]              -> xbf [bt][kt][i8][h][lane][8]
// lane = quad*16+lane16; elem e -> k = kt*64 + h*32 + quad*8 + e.
// =====================================================================
__global__ __launch_bounds__(256) void prep1(
    const float* __restrict__ x, const float* __restrict__ key_kernel,
    const float* __restrict__ kernels, unsigned short* __restrict__ xbf,
    unsigned short* __restrict__ kbf, unsigned short* __restrict__ wkbf) {
  __shared__ float tf[32][65];
  int bid = blockIdx.x;
  int t = threadIdx.x;

  if (bid < 2048) {
    // ---- role T: kernels -> kbf (frag-linear B operand, 32-col tiles) ----
    int m = bid >> 7;
    int rem = bid & 127;
    int a = (rem >> 3) & 15;  // 32-d tile
    int ut64 = rem & 7;       // 64-u tile
    int d0 = a * 32, u0 = ut64 * 64;
    {
      int dr = t >> 4, uc = t & 15;
      const float* src = kernels + ((size_t)m * D_SZ + d0 + dr) * U_SZ + u0 + uc * 4;
      float4 aa = *(const float4*)src;
      float4 bb = *(const float4*)(src + (size_t)16 * U_SZ);
      tf[dr][uc * 4 + 0] = aa.x; tf[dr][uc * 4 + 1] = aa.y;
      tf[dr][uc * 4 + 2] = aa.z; tf[dr][uc * 4 + 3] = aa.w;
      tf[dr + 16][uc * 4 + 0] = bb.x; tf[dr + 16][uc * 4 + 1] = bb.y;
      tf[dr + 16][uc * 4 + 2] = bb.z; tf[dr + 16][uc * 4 + 3] = bb.w;
    }
    __syncthreads();
    {
      int ur = t >> 2, dc = t & 3;  // u-row 0..63, d-oct 0..3
      int kt = a >> 1, h = a & 1;
      int ut16 = ut64 * 2 + (ur >> 5);
      int j2 = (ur >> 4) & 1;
      int lane16 = ur & 15;
      unsigned short* dst = kbf +
          (((((size_t)m * 16 + ut16) * 8 + kt) * 2 + j2) * 2 + h) * 512 +
          ((size_t)dc * 16 + lane16) * 8;
      ushort4 lo, hi;
      lo.x = f2bf(tf[dc * 8 + 0][ur]); lo.y = f2bf(tf[dc * 8 + 1][ur]);
      lo.z = f2bf(tf[dc * 8 + 2][ur]); lo.w = f2bf(tf[dc * 8 + 3][ur]);
      hi.x = f2bf(tf[dc * 8 + 4][ur]); hi.y = f2bf(tf[dc * 8 + 5][ur]);
      hi.z = f2bf(tf[dc * 8 + 6][ur]); hi.w = f2bf(tf[dc * 8 + 7][ur]);
      *(ushort4*)dst = lo;
      *(ushort4*)(dst + 4) = hi;
    }
    return;
  }

  if (bid < 2056) {
    // ---- role W: key_kernel -> wkbf ----
    int kt = bid - 2048;
#pragma unroll
    for (int rep = 0; rep < 2; ++rep) {
      int c = rep * 256 + t;
      int j = c >> 7, h = (c >> 6) & 1, quad = (c >> 4) & 3, ln = c & 15;
      int dd = kt * 64 + h * 32 + quad * 8;
      int u = j * 16 + ln;
      unsigned short v[8];
#pragma unroll
      for (int e = 0; e < 8; ++e)
        v[e] = f2bf(key_kernel[(size_t)(dd + e) * K_SZ + u]);
      unsigned short* dst =
          wkbf + ((size_t)((kt * 4 + j) * 2 + h) * 64 + quad * 16 + ln) * 8;
#pragma unroll
      for (int e = 0; e < 8; ++e) dst[e] = v[e];
    }
    return;
  }

  // ---- role X: x -> xbf (frag-linear A operand) ----
  int xb0 = bid - 2056;
  int bt = xb0 >> 3, i = xb0 & 7;
  int b0 = xb0 * 16;
#pragma unroll
  for (int rep = 0; rep < 4; ++rep) {
    int idx = rep * 256 + t;
    int kt = idx >> 7, h = (idx >> 6) & 1, quad = (idx >> 4) & 3, ln = idx & 15;
    const float* src = x + (size_t)(b0 + ln) * D_SZ + kt * 64 + h * 32 + quad * 8;
    float4 a = *(const float4*)src;
    float4 b = *(const float4*)(src + 4);
    ushort4 lo, hi;
    lo.x = f2bf(a.x); lo.y = f2bf(a.y); lo.z = f2bf(a.z); lo.w = f2bf(a.w);
    hi.x = f2bf(b.x); hi.y = f2bf(b.y); hi.z = f2bf(b.z); hi.w = f2bf(b.w);
    unsigned short* dst =
        xbf + ((((size_t)bt * 8 + kt) * 8 + i) * 2 + h) * 512 +
        ((size_t)quad * 16 + ln) * 8;
    *(ushort4*)dst = lo;
    *(ushort4*)(dst + 4) = hi;
  }
}

// =====================================================================
// poly_gemm (fused): per block (128 rows x 32 cols; 1024 blocks):
//   swizzle: xcd=bid&7 -> ut = xcd*2 + ((bid>>3)&1), bt = bid>>4
//   phase A: keyv[128][64] = x@Wk + bias via MFMA -> LDS (kt loop unroll 1:
//            full unroll batched 96 loads -> spill in rounds 7/8)
//   phase B: sim[16][128] -> LDS. keys_map staged to LDS first; d2[8] per
//            thread (round 8's 512 batched global loads -> 282MB spill)
//   main:    64 iters (8 kt x 8 mi), NO barriers, frags direct global->VGPR
//   epilogue: half-combine via LDS, plain stores.
// =====================================================================
__global__ __launch_bounds__(256, 2) void poly_gemm(
    const unsigned short* __restrict__ xbf,   // A frag-linear
    const unsigned short* __restrict__ kbf,   // B frag-linear
    const unsigned short* __restrict__ wkbf,  // key_kernel frag-linear
    const float* __restrict__ key_bias, const float* __restrict__ keys_map,
    const float* __restrict__ biases, float* __restrict__ out) {
  // 38 KB: kv[128][68] (0..8704) | sKM[16][64] (8704..9728)
  // after phase B: sims[16][128] @ [0..2048) ; sRed @ [2048..6144)
  __shared__ float smem[9728];

  int t = threadIdx.x, w = t >> 6, l = t & 63;
  int bid = blockIdx.x;
  int ut = (bid & 7) * 2 + ((bid >> 3) & 1);
  int bt = bid >> 4;
  int b0 = bt * 128, u0 = ut * 32;
  int lane16 = l & 15, quad = l >> 4;
  float* sKM = smem + 8704;

  // ---------- phase A: keyv (wave w -> rows w*32..w*32+31) ----------
  {
    f32x4 acc[2][4];
#pragma unroll
    for (int ii = 0; ii < 2; ++ii)
#pragma unroll
      for (int j = 0; j < 4; ++j) acc[ii][j] = (f32x4){0.f, 0.f, 0.f, 0.f};
#pragma unroll 1
    for (int kt = 0; kt < 8; ++kt) {
      bf16x8 af[2][2];
#pragma unroll
      for (int ii = 0; ii < 2; ++ii)
#pragma unroll
        for (int h = 0; h < 2; ++h)
          af[ii][h] = *(const bf16x8*)(
              xbf + ((((size_t)bt * 8 + kt) * 8 + w * 2 + ii) * 2 + h) * 512 +
              (size_t)l * 8);
#pragma unroll
      for (int j = 0; j < 4; ++j) {
        bf16x8 bw0 = *(const bf16x8*)(wkbf + ((size_t)((kt * 4 + j) * 2 + 0)) * 512 + (size_t)l * 8);
        bf16x8 bw1 = *(const bf16x8*)(wkbf + ((size_t)((kt * 4 + j) * 2 + 1)) * 512 + (size_t)l * 8);
#pragma unroll
        for (int ii = 0; ii < 2; ++ii) {
          acc[ii][j] = __builtin_amdgcn_mfma_f32_16x16x32_bf16(af[ii][0], bw0, acc[ii][j], 0, 0, 0);
          acc[ii][j] = __builtin_amdgcn_mfma_f32_16x16x32_bf16(af[ii][1], bw1, acc[ii][j], 0, 0, 0);
        }
      }
    }
#pragma unroll
    for (int j = 0; j < 4; ++j) {
      float bc = key_bias[j * 16 + lane16];
#pragma unroll
      for (int ii = 0; ii < 2; ++ii)
#pragma unroll
        for (int r = 0; r < 4; ++r)
          smem[(w * 32 + ii * 16 + quad * 4 + r) * 68 + j * 16 + lane16] =
              acc[ii][j][r] + bc;
    }
  }
  // stage keys_map (4 KB) — covered by the same barrier as kv
  ((float4*)sKM)[t] = ((const float4*)keys_map)[t];
  __syncthreads();

  // ---------- phase B: sim[16][128] via LDS-only reads ----------
  {
    int row = t >> 1, mg = (t & 1) * 8;
    float d2[8] = {0.f, 0.f, 0.f, 0.f, 0.f, 0.f, 0.f, 0.f};
    const float* kvr = smem + row * 68;
#pragma unroll 4
    for (int k = 0; k < 64; ++k) {
      float kvv = kvr[k];
#pragma unroll
      for (int q = 0; q < 8; ++q) {
        float df = kvv - sKM[(mg + q) * 64 + k];
        d2[q] += df * df;
      }
    }
    float s[8];
#pragma unroll
    for (int q = 0; q < 8; ++q) s[q] = 1.0f / (sqrtf(d2[q]) + 1.0f);
    __syncthreads();  // kv reads done; smem[0..2048) reusable as sims
#pragma unroll
    for (int q = 0; q < 8; ++q) smem[(mg + q) * 128 + row] = s[q];
  }
  __syncthreads();

  // ---------- main loop: no barriers ----------
  int half = w >> 1, rw = w & 1;
  f32x4 facc[4][2];
#pragma unroll
  for (int i = 0; i < 4; ++i)
#pragma unroll
    for (int j = 0; j < 2; ++j) facc[i][j] = (f32x4){0.f, 0.f, 0.f, 0.f};

#pragma unroll 1
  for (int kt = 0; kt < 8; ++kt) {
    bf16x8 af[4][2];
#pragma unroll
    for (int ii = 0; ii < 4; ++ii)
#pragma unroll
      for (int h = 0; h < 2; ++h)
        af[ii][h] = *(const bf16x8*)(
            xbf + ((((size_t)bt * 8 + kt) * 8 + rw * 4 + ii) * 2 + h) * 512 +
            (size_t)l * 8);

#pragma unroll 1
    for (int mi = 0; mi < 8; ++mi) {
      int mode = half * 8 + mi;
      const unsigned short* bb =
          kbf + ((((size_t)mode * 16 + ut) * 8 + kt) * 2) * 2 * 512;
      f32x4 sv[4];
#pragma unroll
      for (int i = 0; i < 4; ++i)
        sv[i] = *(const f32x4*)&smem[mode * 128 + rw * 64 + i * 16 + quad * 4];

#pragma unroll
      for (int j = 0; j < 2; ++j) {
        bf16x8 b0f = *(const bf16x8*)(bb + ((size_t)(j * 2 + 0)) * 512 + (size_t)l * 8);
        bf16x8 b1f = *(const bf16x8*)(bb + ((size_t)(j * 2 + 1)) * 512 + (size_t)l * 8);
#pragma unroll
        for (int i = 0; i < 4; ++i) {
          f32x4 p = __builtin_amdgcn_mfma_f32_16x16x32_bf16(
              af[i][0], b0f, (f32x4){0.f, 0.f, 0.f, 0.f}, 0, 0, 0);
          p = __builtin_amdgcn_mfma_f32_16x16x32_bf16(af[i][1], b1f, p, 0, 0, 0);
#pragma unroll
          for (int r = 0; r < 4; ++r) facc[i][j][r] += sv[i][r] * p[r];
        }
      }

      if (kt == 0) {  // bias term once per mode
        float bbv[2];
#pragma unroll
        for (int j = 0; j < 2; ++j)
          bbv[j] = biases[(size_t)mode * U_SZ + u0 + j * 16 + lane16];
#pragma unroll
        for (int i = 0; i < 4; ++i)
#pragma unroll
          for (int j = 0; j < 2; ++j)
#pragma unroll
            for (int r = 0; r < 4; ++r) facc[i][j][r] += sv[i][r] * bbv[j];
      }
    }
  }

  // ---------- epilogue: combine mode-halves via LDS ----------
  float* sRed = smem + 2048;
  __syncthreads();
  if (half == 1) {
#pragma unroll
    for (int i = 0; i < 4; ++i)
#pragma unroll
      for (int r = 0; r < 4; ++r)
#pragma unroll
        for (int j = 0; j < 2; ++j)
          sRed[rw * 2048 + (i * 16 + quad * 4 + r) * 32 + j * 16 + lane16] =
              facc[i][j][r];
  }
  __syncthreads();
  if (half == 0) {
#pragma unroll
    for (int i = 0; i < 4; ++i)
#pragma unroll
      for (int r = 0; r < 4; ++r) {
        int row = b0 + rw * 64 + i * 16 + quad * 4 + r;
        float* orow = out + (size_t)row * U_SZ + u0;
#pragma unroll
        for (int j = 0; j < 2; ++j)
          orow[j * 16 + lane16] =
              (facc[i][j][r] +
               sRed[rw * 2048 + (i * 16 + quad * 4 + r) * 32 + j * 16 + lane16]) *
              0.0625f;
      }
  }
}

extern "C" void kernel_launch(void* const* d_in, const int* in_sizes, int n_in,
                              void* d_out, int out_size, void* d_ws, size_t ws_size,
                              hipStream_t stream) {
  const float* x = (const float*)d_in[0];
  const float* key_kernel = (const float*)d_in[1];
  const float* key_bias = (const float*)d_in[2];
  const float* keys_map = (const float*)d_in[3];
  const float* kernels = (const float*)d_in[4];
  const float* biases = (const float*)d_in[5];
  float* out = (float*)d_out;

  // ws: xbf 8MB | kbf 8MB | wkbf 64KB
  char* p = (char*)d_ws;
  unsigned short* xbf = (unsigned short*)p;  p += (size_t)B_SZ * D_SZ * 2;
  unsigned short* kbf = (unsigned short*)p;  p += (size_t)M_SZ * U_SZ * D_SZ * 2;
  unsigned short* wkbf = (unsigned short*)p;

  prep1<<<dim3(2568), 256, 0, stream>>>(x, key_kernel, kernels, xbf, kbf, wkbf);
  poly_gemm<<<dim3(1024), 256, 0, stream>>>(xbf, kbf, wkbf, key_bias, keys_map,
                                            biases, out);
}

// Round 10
// 175.703 us; speedup vs baseline: 2.1293x; 1.0281x over previous
//
#include <hip/hip_runtime.h>
#include <hip/hip_bf16.h>
#include <stdint.h>

#define B_SZ 8192
#define D_SZ 512
#define U_SZ 512
#define M_SZ 16
#define K_SZ 64

typedef short bf16x8 __attribute__((ext_vector_type(8)));
typedef float f32x4 __attribute__((ext_vector_type(4)));

__device__ __forceinline__ unsigned short f2bf(float f) {
  union { float f; unsigned u; } v; v.f = f;
  unsigned r = v.u + 0x7fffu + ((v.u >> 16) & 1u);
  return (unsigned short)(r >> 16);
}

// =====================================================================
// prep1: role-split single launch. ALL outputs are fragment-linear bf16.
//  [0,2048):    kernels [M][D][U] f32 -> kbf [m][ut16][kt][j2][h][lane][8]
//  [2048,2056): key_kernel [D][K]     -> wkbf [kt][j4][h][lane][8]
//  [2056,2568): x [B][D]              -> xbf [bt][kt][i8][h][lane][8]
//               (role X: LDS-staged — direct form had 2KB-stride lane
//                addresses = 64 scattered requests/instr, ~75 us)
// =====================================================================
__global__ __launch_bounds__(256) void prep1(
    const float* __restrict__ x, const float* __restrict__ key_kernel,
    const float* __restrict__ kernels, unsigned short* __restrict__ xbf,
    unsigned short* __restrict__ kbf, unsigned short* __restrict__ wkbf) {
  __shared__ float ps[16 * 516];  // 33 KB; role T uses first 2080 floats
  int bid = blockIdx.x;
  int t = threadIdx.x;

  if (bid < 2048) {
    // ---- role T: kernels -> kbf (frag-linear B operand, 32-col tiles) ----
    float(*tf)[65] = (float(*)[65])ps;
    int m = bid >> 7;
    int rem = bid & 127;
    int a = (rem >> 3) & 15;  // 32-d tile
    int ut64 = rem & 7;       // 64-u tile
    int d0 = a * 32, u0 = ut64 * 64;
    {
      int dr = t >> 4, uc = t & 15;
      const float* src = kernels + ((size_t)m * D_SZ + d0 + dr) * U_SZ + u0 + uc * 4;
      float4 aa = *(const float4*)src;
      float4 bb = *(const float4*)(src + (size_t)16 * U_SZ);
      tf[dr][uc * 4 + 0] = aa.x; tf[dr][uc * 4 + 1] = aa.y;
      tf[dr][uc * 4 + 2] = aa.z; tf[dr][uc * 4 + 3] = aa.w;
      tf[dr + 16][uc * 4 + 0] = bb.x; tf[dr + 16][uc * 4 + 1] = bb.y;
      tf[dr + 16][uc * 4 + 2] = bb.z; tf[dr + 16][uc * 4 + 3] = bb.w;
    }
    __syncthreads();
    {
      int ur = t >> 2, dc = t & 3;  // u-row 0..63, d-oct 0..3
      int kt = a >> 1, h = a & 1;
      int ut16 = ut64 * 2 + (ur >> 5);
      int j2 = (ur >> 4) & 1;
      int lane16 = ur & 15;
      unsigned short* dst = kbf +
          (((((size_t)m * 16 + ut16) * 8 + kt) * 2 + j2) * 2 + h) * 512 +
          ((size_t)dc * 16 + lane16) * 8;
      ushort4 lo, hi;
      lo.x = f2bf(tf[dc * 8 + 0][ur]); lo.y = f2bf(tf[dc * 8 + 1][ur]);
      lo.z = f2bf(tf[dc * 8 + 2][ur]); lo.w = f2bf(tf[dc * 8 + 3][ur]);
      hi.x = f2bf(tf[dc * 8 + 4][ur]); hi.y = f2bf(tf[dc * 8 + 5][ur]);
      hi.z = f2bf(tf[dc * 8 + 6][ur]); hi.w = f2bf(tf[dc * 8 + 7][ur]);
      *(ushort4*)dst = lo;
      *(ushort4*)(dst + 4) = hi;
    }
    return;
  }

  if (bid < 2056) {
    // ---- role W: key_kernel -> wkbf ----
    int kt = bid - 2048;
#pragma unroll
    for (int rep = 0; rep < 2; ++rep) {
      int c = rep * 256 + t;
      int j = c >> 7, h = (c >> 6) & 1, quad = (c >> 4) & 3, ln = c & 15;
      int dd = kt * 64 + h * 32 + quad * 8;
      int u = j * 16 + ln;
      unsigned short v[8];
#pragma unroll
      for (int e = 0; e < 8; ++e)
        v[e] = f2bf(key_kernel[(size_t)(dd + e) * K_SZ + u]);
      unsigned short* dst =
          wkbf + ((size_t)((kt * 4 + j) * 2 + h) * 64 + quad * 16 + ln) * 8;
#pragma unroll
      for (int e = 0; e < 8; ++e) dst[e] = v[e];
    }
    return;
  }

  // ---- role X: x -> xbf via LDS (coalesced reads, conflict-free b128) ----
  int xb0 = bid - 2056;
  int bt = xb0 >> 3, i = xb0 & 7;
  int b0 = xb0 * 16;
  // stage 16 rows x 512 f32: lanes sweep columns (1KB contiguous per wave)
#pragma unroll
  for (int p2 = 0; p2 < 8; ++p2) {
    int idx = p2 * 256 + t;
    int r = idx >> 7, c4 = idx & 127;
    float4 v = *(const float4*)(x + (size_t)(b0 + r) * 512 + c4 * 4);
    *(float4*)&ps[r * 516 + c4 * 4] = v;  // stride 2064 B (16-aligned)
  }
  __syncthreads();
#pragma unroll
  for (int rep = 0; rep < 4; ++rep) {
    int idx = rep * 256 + t;
    int kt = idx >> 7, h = (idx >> 6) & 1, quad = (idx >> 4) & 3, ln = idx & 15;
    int col = kt * 64 + h * 32 + quad * 8;
    float4 a = *(const float4*)&ps[ln * 516 + col];
    float4 b = *(const float4*)&ps[ln * 516 + col + 4];
    ushort4 lo, hi;
    lo.x = f2bf(a.x); lo.y = f2bf(a.y); lo.z = f2bf(a.z); lo.w = f2bf(a.w);
    hi.x = f2bf(b.x); hi.y = f2bf(b.y); hi.z = f2bf(b.z); hi.w = f2bf(b.w);
    unsigned short* dst =
        xbf + ((((size_t)bt * 8 + kt) * 8 + i) * 2 + h) * 512 +
        ((size_t)quad * 16 + ln) * 8;
    *(ushort4*)dst = lo;
    *(ushort4*)(dst + 4) = hi;
  }
}

// =====================================================================
// poly_gemm (fused): 1024 blocks = 64 bt x 16 ut (xcd-swizzled).
//   phase A: keyv[128][69-stride] via MFMA -> LDS (kt unroll 1)
//   phase B: sim[16][128] -> LDS; kv stride 69 (5r mod 32 -> conflict-free)
//   main:    8 kt x 8 mi, no barriers; round-6-style body (all frags
//            loaded up-front per iter -> high-ILP ~110-reg schedule)
//   epilogue: half-combine via LDS.
// =====================================================================
__global__ __launch_bounds__(256, 2) void poly_gemm(
    const unsigned short* __restrict__ xbf,   // A frag-linear
    const unsigned short* __restrict__ kbf,   // B frag-linear
    const unsigned short* __restrict__ wkbf,  // key_kernel frag-linear
    const float* __restrict__ key_bias, const float* __restrict__ keys_map,
    const float* __restrict__ biases, float* __restrict__ out) {
  // kv[128][69] @ [0,8832) | sKM[16][64] @ [8832,9856)
  // after phase B: sims[16][128] @ [0,2048) ; sRed @ [2048,6144)
  __shared__ float smem[9856];

  int t = threadIdx.x, w = t >> 6, l = t & 63;
  int bid = blockIdx.x;
  int ut = (bid & 7) * 2 + ((bid >> 3) & 1);
  int bt = bid >> 4;
  int b0 = bt * 128, u0 = ut * 32;
  int lane16 = l & 15, quad = l >> 4;
  float* sKM = smem + 8832;

  // ---------- phase A: keyv (wave w -> rows w*32..w*32+31) ----------
  {
    f32x4 acc[2][4];
#pragma unroll
    for (int ii = 0; ii < 2; ++ii)
#pragma unroll
      for (int j = 0; j < 4; ++j) acc[ii][j] = (f32x4){0.f, 0.f, 0.f, 0.f};
#pragma unroll 1
    for (int kt = 0; kt < 8; ++kt) {
      bf16x8 af[2][2];
#pragma unroll
      for (int ii = 0; ii < 2; ++ii)
#pragma unroll
        for (int h = 0; h < 2; ++h)
          af[ii][h] = *(const bf16x8*)(
              xbf + ((((size_t)bt * 8 + kt) * 8 + w * 2 + ii) * 2 + h) * 512 +
              (size_t)l * 8);
#pragma unroll
      for (int j = 0; j < 4; ++j) {
        bf16x8 bw0 = *(const bf16x8*)(wkbf + ((size_t)((kt * 4 + j) * 2 + 0)) * 512 + (size_t)l * 8);
        bf16x8 bw1 = *(const bf16x8*)(wkbf + ((size_t)((kt * 4 + j) * 2 + 1)) * 512 + (size_t)l * 8);
#pragma unroll
        for (int ii = 0; ii < 2; ++ii) {
          acc[ii][j] = __builtin_amdgcn_mfma_f32_16x16x32_bf16(af[ii][0], bw0, acc[ii][j], 0, 0, 0);
          acc[ii][j] = __builtin_amdgcn_mfma_f32_16x16x32_bf16(af[ii][1], bw1, acc[ii][j], 0, 0, 0);
        }
      }
    }
#pragma unroll
    for (int j = 0; j < 4; ++j) {
      float bc = key_bias[j * 16 + lane16];
#pragma unroll
      for (int ii = 0; ii < 2; ++ii)
#pragma unroll
        for (int r = 0; r < 4; ++r)
          smem[(w * 32 + ii * 16 + quad * 4 + r) * 69 + j * 16 + lane16] =
              acc[ii][j][r] + bc;
    }
  }
  ((float4*)sKM)[t] = ((const float4*)keys_map)[t];
  __syncthreads();

  // ---------- phase B: sim[16][128], LDS-only reads ----------
  {
    int row = t >> 1, mg = (t & 1) * 8;
    float d2[8] = {0.f, 0.f, 0.f, 0.f, 0.f, 0.f, 0.f, 0.f};
    const float* kvr = smem + row * 69;
#pragma unroll 4
    for (int k = 0; k < 64; ++k) {
      float kvv = kvr[k];
#pragma unroll
      for (int q = 0; q < 8; ++q) {
        float df = kvv - sKM[(mg + q) * 64 + k];
        d2[q] += df * df;
      }
    }
    float s[8];
#pragma unroll
    for (int q = 0; q < 8; ++q) s[q] = 1.0f / (sqrtf(d2[q]) + 1.0f);
    __syncthreads();  // kv reads done; smem[0,2048) reusable as sims
#pragma unroll
    for (int q = 0; q < 8; ++q) smem[(mg + q) * 128 + row] = s[q];
  }
  __syncthreads();

  // ---------- main loop: no barriers ----------
  int half = w >> 1, rw = w & 1;
  f32x4 facc[4][2];
#pragma unroll
  for (int i = 0; i < 4; ++i)
#pragma unroll
    for (int j = 0; j < 2; ++j) facc[i][j] = (f32x4){0.f, 0.f, 0.f, 0.f};

#pragma unroll 1
  for (int kt = 0; kt < 8; ++kt) {
    bf16x8 af[4][2];
#pragma unroll
    for (int ii = 0; ii < 4; ++ii)
#pragma unroll
      for (int h = 0; h < 2; ++h)
        af[ii][h] = *(const bf16x8*)(
            xbf + ((((size_t)bt * 8 + kt) * 8 + rw * 4 + ii) * 2 + h) * 512 +
            (size_t)l * 8);

#pragma unroll 2
    for (int mi = 0; mi < 8; ++mi) {
      int mode = half * 8 + mi;
      const unsigned short* bb =
          kbf + ((((size_t)mode * 16 + ut) * 8 + kt) * 2) * 2 * 512;
      bf16x8 bfr[2][2];
#pragma unroll
      for (int j = 0; j < 2; ++j)
#pragma unroll
        for (int h = 0; h < 2; ++h)
          bfr[j][h] = *(const bf16x8*)(bb + ((size_t)(j * 2 + h)) * 512 +
                                       (size_t)l * 8);
      f32x4 sv[4];
#pragma unroll
      for (int i = 0; i < 4; ++i)
        sv[i] = *(const f32x4*)&smem[mode * 128 + rw * 64 + i * 16 + quad * 4];

#pragma unroll
      for (int i = 0; i < 4; ++i)
#pragma unroll
        for (int j = 0; j < 2; ++j) {
          f32x4 p = __builtin_amdgcn_mfma_f32_16x16x32_bf16(
              af[i][0], bfr[j][0], (f32x4){0.f, 0.f, 0.f, 0.f}, 0, 0, 0);
          p = __builtin_amdgcn_mfma_f32_16x16x32_bf16(af[i][1], bfr[j][1], p, 0, 0, 0);
#pragma unroll
          for (int r = 0; r < 4; ++r) facc[i][j][r] += sv[i][r] * p[r];
        }

      if (kt == 0) {  // bias term once per mode
        float bbv[2];
#pragma unroll
        for (int j = 0; j < 2; ++j)
          bbv[j] = biases[(size_t)mode * U_SZ + u0 + j * 16 + lane16];
#pragma unroll
        for (int i = 0; i < 4; ++i)
#pragma unroll
          for (int j = 0; j < 2; ++j)
#pragma unroll
            for (int r = 0; r < 4; ++r) facc[i][j][r] += sv[i][r] * bbv[j];
      }
    }
  }

  // ---------- epilogue: combine mode-halves via LDS ----------
  float* sRed = smem + 2048;
  __syncthreads();
  if (half == 1) {
#pragma unroll
    for (int i = 0; i < 4; ++i)
#pragma unroll
      for (int r = 0; r < 4; ++r)
#pragma unroll
        for (int j = 0; j < 2; ++j)
          sRed[rw * 2048 + (i * 16 + quad * 4 + r) * 32 + j * 16 + lane16] =
              facc[i][j][r];
  }
  __syncthreads();
  if (half == 0) {
#pragma unroll
    for (int i = 0; i < 4; ++i)
#pragma unroll
      for (int r = 0; r < 4; ++r) {
        int row = b0 + rw * 64 + i * 16 + quad * 4 + r;
        float* orow = out + (size_t)row * U_SZ + u0;
#pragma unroll
        for (int j = 0; j < 2; ++j)
          orow[j * 16 + lane16] =
              (facc[i][j][r] +
               sRed[rw * 2048 + (i * 16 + quad * 4 + r) * 32 + j * 16 + lane16]) *
              0.0625f;
      }
  }
}

extern "C" void kernel_launch(void* const* d_in, const int* in_sizes, int n_in,
                              void* d_out, int out_size, void* d_ws, size_t ws_size,
                              hipStream_t stream) {
  const float* x = (const float*)d_in[0];
  const float* key_kernel = (const float*)d_in[1];
  const float* key_bias = (const float*)d_in[2];
  const float* keys_map = (const float*)d_in[3];
  const float* kernels = (const float*)d_in[4];
  const float* biases = (const float*)d_in[5];
  float* out = (float*)d_out;

  // ws: xbf 8MB | kbf 8MB | wkbf 64KB
  char* p = (char*)d_ws;
  unsigned short* xbf = (unsigned short*)p;  p += (size_t)B_SZ * D_SZ * 2;
  unsigned short* kbf = (unsigned short*)p;  p += (size_t)M_SZ * U_SZ * D_SZ * 2;
  unsigned short* wkbf = (unsigned short*)p;

  prep1<<<dim3(2568), 256, 0, stream>>>(x, key_kernel, kernels, xbf, kbf, wkbf);
  poly_gemm<<<dim3(1024), 256, 0, stream>>>(xbf, kbf, wkbf, key_bias, keys_map,
                                            biases, out);
}